// Round 2
// baseline (169.204 us; speedup 1.0000x reference)
//
#include <hip/hip_runtime.h>

// BlockDiagonalLinear hyperbolic layer, fused, LDS-free matvec.
// out = gamma(row) * (x @ blockdiag(W)^T), gamma computed analytically from
// ||x|| and ||x@W^T|| (expmap0 scale c folds into gamma).
//
// Structure: grid 512 x 1024 threads (16 waves). WG owns 16 rows; wave w owns
// diagonal block w (cols 256w..256w+255) -- block-diagonality means waves
// partition the columns with no sharing, so A fragments are loaded straight
// from global x (fp32->bf16 in-register), fused with the ||x||^2 partial.
// B fragments from a bf16 copy of W in d_ws (2 MiB, L2-resident).
// acc[16] = 64 VGPRs; launch_bounds(1024,4) targets 16 waves/CU.

typedef __attribute__((ext_vector_type(8))) short short8;
typedef __attribute__((ext_vector_type(4))) float f32x4;

__device__ __forceinline__ ushort f2bf(float f) {
  uint u = __float_as_uint(f);
  return (ushort)((u + 0x7fffu + ((u >> 16) & 1u)) >> 16);  // RNE
}

__global__ __launch_bounds__(256) void wconv_kernel(const float* __restrict__ w,
                                                    ushort* __restrict__ wb) {
  int i = blockIdx.x * blockDim.x + threadIdx.x;  // 262144 float4s total
  float4 v = reinterpret_cast<const float4*>(w)[i];
  uint2 p;
  p.x = (uint)f2bf(v.x) | ((uint)f2bf(v.y) << 16);
  p.y = (uint)f2bf(v.z) | ((uint)f2bf(v.w) << 16);
  reinterpret_cast<uint2*>(wb)[i] = p;
}

template <bool WS>
__global__ __launch_bounds__(1024, 4) void hyp_kernel(const float* __restrict__ x,
                                                      const float* __restrict__ wf,
                                                      const ushort* __restrict__ wb,
                                                      float* __restrict__ out) {
  __shared__ float ssxp[16][16];  // [wave][row] partial ||x||^2
  __shared__ float sspm[16][16];  // [wave][row] partial ||mx'||^2
  __shared__ float gam[16];       // per-row output scale

  const int tid = threadIdx.x;
  const int w = tid >> 6;   // wave id == diagonal block id
  const int lane = tid & 63;
  const int g = lane >> 4;  // k-group (A/B) / row-group (C)
  const int q = lane & 15;  // row (A) / col (B,C) within fragment
  const size_t rowbase = (size_t)blockIdx.x * 16;

  f32x4 acc[16];
#pragma unroll
  for (int nt = 0; nt < 16; ++nt) acc[nt] = (f32x4){0.f, 0.f, 0.f, 0.f};

  // Per-lane pointers: x row q, this wave's 256-col slice, k-subgroup g.
  const float* xbase = x + (rowbase + q) * 4096 + w * 256 + g * 8;
  const ushort* wbbase = WS ? (wb + ((size_t)w << 16) + (size_t)q * 256 + g * 8) : nullptr;
  const float* wfbase = WS ? nullptr : (wf + ((size_t)w << 16) + (size_t)q * 256 + g * 8);

  float ssx = 0.f;
  for (int kf = 0; kf < 8; ++kf) {
    const float* xp = xbase + kf * 32;
    float4 v0 = *reinterpret_cast<const float4*>(xp);
    float4 v1 = *reinterpret_cast<const float4*>(xp + 4);
    ssx += v0.x * v0.x + v0.y * v0.y + v0.z * v0.z + v0.w * v0.w +
           v1.x * v1.x + v1.y * v1.y + v1.z * v1.z + v1.w * v1.w;
    short8 afr;
    afr[0] = (short)f2bf(v0.x); afr[1] = (short)f2bf(v0.y);
    afr[2] = (short)f2bf(v0.z); afr[3] = (short)f2bf(v0.w);
    afr[4] = (short)f2bf(v1.x); afr[5] = (short)f2bf(v1.y);
    afr[6] = (short)f2bf(v1.z); afr[7] = (short)f2bf(v1.w);
#pragma unroll
    for (int nt = 0; nt < 16; ++nt) {
      short8 bfr;  // B[k][n] = W[w][nt*16+q][k]: contiguous in k
      if (WS) {
        bfr = *reinterpret_cast<const short8*>(wbbase + nt * 4096 + kf * 32);
      } else {
        const float* wp = wfbase + nt * 4096 + kf * 32;
        float4 w0 = *reinterpret_cast<const float4*>(wp);
        float4 w1 = *reinterpret_cast<const float4*>(wp + 4);
        bfr[0] = (short)f2bf(w0.x); bfr[1] = (short)f2bf(w0.y);
        bfr[2] = (short)f2bf(w0.z); bfr[3] = (short)f2bf(w0.w);
        bfr[4] = (short)f2bf(w1.x); bfr[5] = (short)f2bf(w1.y);
        bfr[6] = (short)f2bf(w1.z); bfr[7] = (short)f2bf(w1.w);
      }
      acc[nt] = __builtin_amdgcn_mfma_f32_16x16x32_bf16(afr, bfr, acc[nt], 0, 0, 0);
    }
  }

  // ||x||^2 partial: combine the 4 g-groups (same row q) across the wave.
  ssx += __shfl_xor(ssx, 16, 64);
  ssx += __shfl_xor(ssx, 32, 64);
  if (g == 0) ssxp[w][q] = ssx;

  // ||mx'||^2 partial: sum acc^2 over this wave's 256 cols, per row g*4+j.
  float s0 = 0.f, s1 = 0.f, s2a = 0.f, s3 = 0.f;
#pragma unroll
  for (int nt = 0; nt < 16; ++nt) {
    f32x4 a = acc[nt];
    s0 += a[0] * a[0];
    s1 += a[1] * a[1];
    s2a += a[2] * a[2];
    s3 += a[3] * a[3];
  }
#pragma unroll
  for (int m = 1; m < 16; m <<= 1) {
    s0 += __shfl_xor(s0, m, 64);
    s1 += __shfl_xor(s1, m, 64);
    s2a += __shfl_xor(s2a, m, 64);
    s3 += __shfl_xor(s3, m, 64);
  }
  if (q == 0) {
    sspm[w][g * 4 + 0] = s0;
    sspm[w][g * 4 + 1] = s1;
    sspm[w][g * 4 + 2] = s2a;
    sspm[w][g * 4 + 3] = s3;
  }
  __syncthreads();

  if (tid < 16) {
    float sx = 0.f, s2 = 0.f;
#pragma unroll
    for (int ww = 0; ww < 16; ++ww) {
      sx += ssxp[ww][tid];
      s2 += sspm[ww][tid];
    }
    const float xnorm = sqrtf(sx);
    const float un = fmaxf(xnorm, 1e-5f);
    const float a0 = 0.1f * un;
    const float th = tanhf(fminf(a0, 15.f));
    const float c = th / a0;             // h = c * x
    const float hn = th * (xnorm / a0);  // ||h||
    const float xn = fmaxf(hn, 1e-5f);
    const float sp = sqrtf(s2);          // ||mx'||
    float gt = 0.f;
    if (sp > 0.f) {
      const float s = c * sp;  // ||mx||
      const float xc = fminf(0.1f * xn, 1.f - 1e-5f);
      const float at = 0.5f * logf((1.f + xc) / (1.f - xc));  // artanh
      const float t = (s / xn) * at;
      const float tn = tanhf(fminf(t, 15.f));
      const float alpha = tn / (0.1f * s);  // res_c = alpha * mx
      const float rn = tn * 10.f;           // ||res_c||
      const float nrm = fmaxf(rn, 1e-5f);
      const float proj = (nrm > 9.99f) ? (9.99f / nrm) : 1.f;  // _project
      const float yn = fmaxf(rn * proj, 1e-5f);
      const float yc = fminf(0.1f * yn, 1.f - 1e-5f);
      const float at2 = 0.5f * logf((1.f + yc) / (1.f - yc));
      gt = c * alpha * proj * (at2 / (0.1f * yn));  // logmap0 + fold of c
    }
    gam[tid] = gt;
  }
  __syncthreads();

  // Store: out = gamma(row) * mx'
  float gr[4];
#pragma unroll
  for (int j = 0; j < 4; ++j) gr[j] = gam[g * 4 + j];
  float* orow = out + rowbase * 4096 + w * 256;
#pragma unroll
  for (int nt = 0; nt < 16; ++nt) {
    const int col = nt * 16 + q;
    f32x4 a = acc[nt];
#pragma unroll
    for (int j = 0; j < 4; ++j) {
      orow[(size_t)(g * 4 + j) * 4096 + col] = gr[j] * a[j];
    }
  }
}

extern "C" void kernel_launch(void* const* d_in, const int* in_sizes, int n_in,
                              void* d_out, int out_size, void* d_ws, size_t ws_size,
                              hipStream_t stream) {
  const float* x = (const float*)d_in[0];   // [4,2048,4096] f32
  const float* w = (const float*)d_in[1];   // [16,256,256] f32
  float* out = (float*)d_out;               // [4,2048,4096] f32

  const size_t wb_bytes = (size_t)16 * 256 * 256 * sizeof(ushort);  // 2 MiB
  if (ws_size >= wb_bytes) {
    ushort* wb = (ushort*)d_ws;
    wconv_kernel<<<1024, 256, 0, stream>>>(w, wb);
    hyp_kernel<true><<<512, 1024, 0, stream>>>(x, w, wb, out);
  } else {
    hyp_kernel<false><<<512, 1024, 0, stream>>>(x, w, nullptr, out);
  }
}

// Round 3
// 116.066 us; speedup vs baseline: 1.4578x; 1.4578x over previous
//
#include <hip/hip_runtime.h>

// BlockDiagonalLinear hyperbolic layer, fused. Round 3: kill the scattered
// VMEM (TA-bound theory). All global memory instructions are wave-contiguous:
//   - W repacked in d_ws as [w][kf][nt][lane][8 bf16]: B-frag = contiguous 1KB
//   - x staged via LDS: coalesced row loads -> bf16 XOR-swizzled LDS ->
//     ds_read_b128 A-fragments
//   - out bounced through LDS (f32, two col-half passes) -> contiguous
//     dwordx4 row stores
// WG = 1024 thr (16 waves), 16 rows/WG, wave w owns diagonal block w.

typedef __attribute__((ext_vector_type(8))) short short8;
typedef __attribute__((ext_vector_type(4))) float f32x4;

__device__ __forceinline__ ushort f2bf(float f) {
  uint u = __float_as_uint(f);
  return (ushort)((u + 0x7fffu + ((u >> 16) & 1u)) >> 16);  // RNE
}

// Repack W f32 [16][256][256] -> bf16 wb2[w][kf][nt][lane][8]
// such that the B fragment for (w,kf,nt) is contiguous across the wave.
__global__ __launch_bounds__(256) void wrepack_kernel(const float* __restrict__ w,
                                                      ushort* __restrict__ wb2) {
  int idx = blockIdx.x * blockDim.x + threadIdx.x;  // 16*8*16*64 = 131072
  int lane = idx & 63;
  int nt = (idx >> 6) & 15;
  int kf = (idx >> 10) & 7;
  int blk = idx >> 13;
  int g = lane >> 4, q = lane & 15;
  const float* src = w + ((size_t)blk << 16) + (size_t)(nt * 16 + q) * 256 + kf * 32 + g * 8;
  float4 v0 = *reinterpret_cast<const float4*>(src);
  float4 v1 = *reinterpret_cast<const float4*>(src + 4);
  ushort o[8] = {f2bf(v0.x), f2bf(v0.y), f2bf(v0.z), f2bf(v0.w),
                 f2bf(v1.x), f2bf(v1.y), f2bf(v1.z), f2bf(v1.w)};
  uint4 p;
  p.x = (uint)o[0] | ((uint)o[1] << 16);
  p.y = (uint)o[2] | ((uint)o[3] << 16);
  p.z = (uint)o[4] | ((uint)o[5] << 16);
  p.w = (uint)o[6] | ((uint)o[7] << 16);
  reinterpret_cast<uint4*>(wb2)[idx] = p;  // 16B contiguous per lane
}

__global__ __launch_bounds__(1024, 4) void hyp_kernel(const float* __restrict__ x,
                                                      const ushort* __restrict__ wb2,
                                                      float* __restrict__ out) {
  __shared__ ushort xs[16 * 4096];  // 128 KiB: bf16 x tile, then reused as f32 out bounce
  __shared__ float ssxp[16];        // per-row ||x||^2
  __shared__ float sspm[16][16];    // [wave][row] partial ||mx'||^2
  __shared__ float gam[16];         // per-row output scale

  const int tid = threadIdx.x;
  const int w = tid >> 6;   // wave id == diagonal block id == staged row id
  const int lane = tid & 63;
  const int g = lane >> 4;
  const int q = lane & 15;
  const size_t rowbase = (size_t)blockIdx.x * 16;

  // ---- Phase 1: stage x row w (coalesced), fused ||x||^2 ----
  {
    const float4* xr = reinterpret_cast<const float4*>(x + (rowbase + w) * 4096);
    char* xrow = reinterpret_cast<char*>(xs);
    const uint sw = (uint)(w & 7) << 4;
    float ss = 0.f;
#pragma unroll
    for (int chunk = 0; chunk < 16; ++chunk) {
      float4 v = xr[chunk * 64 + lane];  // lane-contiguous 16B
      ss += v.x * v.x + v.y * v.y + v.z * v.z + v.w * v.w;
      uint2 p;
      p.x = (uint)f2bf(v.x) | ((uint)f2bf(v.y) << 16);
      p.y = (uint)f2bf(v.z) | ((uint)f2bf(v.w) << 16);
      uint byte = ((uint)(w * 8192 + (chunk * 64 + lane) * 8)) ^ sw;
      *reinterpret_cast<uint2*>(xrow + byte) = p;
    }
#pragma unroll
    for (int m = 32; m; m >>= 1) ss += __shfl_xor(ss, m, 64);
    if (lane == 0) ssxp[w] = ss;
  }
  __syncthreads();

  // ---- Phase 2: MFMA. wave w -> block w, A from LDS, B from repacked wb2 ----
  f32x4 acc[16];
#pragma unroll
  for (int nt = 0; nt < 16; ++nt) acc[nt] = (f32x4){0.f, 0.f, 0.f, 0.f};

  for (int kf = 0; kf < 8; ++kf) {
    uint abyte = ((uint)(q * 8192 + w * 512 + kf * 64 + g * 16)) ^ ((uint)(q & 7) << 4);
    short8 afr = *reinterpret_cast<const short8*>(reinterpret_cast<const char*>(xs) + abyte);
    const ushort* bkf = wb2 + ((((size_t)w * 8 + kf) * 16) << 9) + (lane << 3);
#pragma unroll
    for (int nt = 0; nt < 16; ++nt) {
      short8 bfr = *reinterpret_cast<const short8*>(bkf + (nt << 9));  // contiguous 1KB/wave
      acc[nt] = __builtin_amdgcn_mfma_f32_16x16x32_bf16(afr, bfr, acc[nt], 0, 0, 0);
    }
  }

  // ---- Phase 3: per-row ||mx'||^2 partials, then gamma ----
  {
    float s0 = 0.f, s1 = 0.f, s2a = 0.f, s3 = 0.f;
#pragma unroll
    for (int nt = 0; nt < 16; ++nt) {
      f32x4 a = acc[nt];
      s0 += a[0] * a[0];
      s1 += a[1] * a[1];
      s2a += a[2] * a[2];
      s3 += a[3] * a[3];
    }
#pragma unroll
    for (int m = 1; m < 16; m <<= 1) {
      s0 += __shfl_xor(s0, m, 64);
      s1 += __shfl_xor(s1, m, 64);
      s2a += __shfl_xor(s2a, m, 64);
      s3 += __shfl_xor(s3, m, 64);
    }
    if (q == 0) {
      sspm[w][g * 4 + 0] = s0;
      sspm[w][g * 4 + 1] = s1;
      sspm[w][g * 4 + 2] = s2a;
      sspm[w][g * 4 + 3] = s3;
    }
  }
  __syncthreads();  // sspm complete; also last read of xs bf16 data done

  if (tid < 16) {
    float s2 = 0.f;
#pragma unroll
    for (int ww = 0; ww < 16; ++ww) s2 += sspm[ww][tid];
    const float xnorm = sqrtf(ssxp[tid]);
    const float un = fmaxf(xnorm, 1e-5f);
    const float a0 = 0.1f * un;
    const float th = tanhf(fminf(a0, 15.f));
    const float c = th / a0;             // h = c * x
    const float hn = th * (xnorm / a0);  // ||h||
    const float xn = fmaxf(hn, 1e-5f);
    const float sp = sqrtf(s2);          // ||mx'||
    float gt = 0.f;
    if (sp > 0.f) {
      const float s = c * sp;  // ||mx||
      const float xc = fminf(0.1f * xn, 1.f - 1e-5f);
      const float at = 0.5f * logf((1.f + xc) / (1.f - xc));  // artanh
      const float t = (s / xn) * at;
      const float tn = tanhf(fminf(t, 15.f));
      const float alpha = tn / (0.1f * s);  // res_c = alpha * mx
      const float rn = tn * 10.f;           // ||res_c||
      const float nrm = fmaxf(rn, 1e-5f);
      const float proj = (nrm > 9.99f) ? (9.99f / nrm) : 1.f;  // _project
      const float yn = fmaxf(rn * proj, 1e-5f);
      const float yc = fminf(0.1f * yn, 1.f - 1e-5f);
      const float at2 = 0.5f * logf((1.f + yc) / (1.f - yc));
      gt = c * alpha * proj * (at2 / (0.1f * yn));  // logmap0 + fold of c
    }
    gam[tid] = gt;
  }
  __syncthreads();

  // ---- Phase 4: out = gamma * mx', bounced through LDS for coalesced stores.
  // Two passes: pass p covers cols [p*2048, p*2048+2048), f32 in reused xs.
  char* ob = reinterpret_cast<char*>(xs);
  float gr[4];
#pragma unroll
  for (int j = 0; j < 4; ++j) gr[j] = gam[g * 4 + j];

#pragma unroll
  for (int p = 0; p < 2; ++p) {
    if ((w >> 3) == p) {
      const int wl = w & 7;
#pragma unroll
      for (int nt = 0; nt < 16; ++nt) {
#pragma unroll
        for (int j = 0; j < 4; ++j) {
          const int row = g * 4 + j;
          const int col = wl * 256 + nt * 16 + q;
          uint byte = ((uint)(row * 8192 + col * 4)) ^ ((uint)(row & 7) << 4);
          *reinterpret_cast<float*>(ob + byte) = gr[j] * acc[nt][j];
        }
      }
    }
    __syncthreads();
    {
      const char* rb = ob + w * 8192;
      const uint sw = (uint)(w & 7) << 4;
      float* op = out + (rowbase + w) * 4096 + p * 2048;
#pragma unroll
      for (int i = 0; i < 8; ++i) {
        uint byte = ((uint)(lane * 16 + i * 1024)) ^ sw;
        f32x4 v = *reinterpret_cast<const f32x4*>(rb + byte);
        *reinterpret_cast<f32x4*>(op + lane * 4 + i * 256) = v;  // contiguous 1KB/wave
      }
    }
    __syncthreads();
  }
}

// Fallback (no workspace): round-2 style, W read directly (scattered, slow but correct).
__global__ __launch_bounds__(1024, 4) void hyp_fallback(const float* __restrict__ x,
                                                        const float* __restrict__ wf,
                                                        float* __restrict__ out) {
  __shared__ float ssxp[16][16];
  __shared__ float sspm[16][16];
  __shared__ float gam[16];
  const int tid = threadIdx.x;
  const int w = tid >> 6;
  const int lane = tid & 63;
  const int g = lane >> 4, q = lane & 15;
  const size_t rowbase = (size_t)blockIdx.x * 16;
  f32x4 acc[16];
#pragma unroll
  for (int nt = 0; nt < 16; ++nt) acc[nt] = (f32x4){0.f, 0.f, 0.f, 0.f};
  const float* xbase = x + (rowbase + q) * 4096 + w * 256 + g * 8;
  const float* wfbase = wf + ((size_t)w << 16) + (size_t)q * 256 + g * 8;
  float ssx = 0.f;
  for (int kf = 0; kf < 8; ++kf) {
    const float* xp = xbase + kf * 32;
    float4 v0 = *reinterpret_cast<const float4*>(xp);
    float4 v1 = *reinterpret_cast<const float4*>(xp + 4);
    ssx += v0.x * v0.x + v0.y * v0.y + v0.z * v0.z + v0.w * v0.w +
           v1.x * v1.x + v1.y * v1.y + v1.z * v1.z + v1.w * v1.w;
    short8 afr;
    afr[0] = (short)f2bf(v0.x); afr[1] = (short)f2bf(v0.y);
    afr[2] = (short)f2bf(v0.z); afr[3] = (short)f2bf(v0.w);
    afr[4] = (short)f2bf(v1.x); afr[5] = (short)f2bf(v1.y);
    afr[6] = (short)f2bf(v1.z); afr[7] = (short)f2bf(v1.w);
#pragma unroll
    for (int nt = 0; nt < 16; ++nt) {
      const float* wp = wfbase + nt * 4096 + kf * 32;
      float4 w0 = *reinterpret_cast<const float4*>(wp);
      float4 w1 = *reinterpret_cast<const float4*>(wp + 4);
      short8 bfr;
      bfr[0] = (short)f2bf(w0.x); bfr[1] = (short)f2bf(w0.y);
      bfr[2] = (short)f2bf(w0.z); bfr[3] = (short)f2bf(w0.w);
      bfr[4] = (short)f2bf(w1.x); bfr[5] = (short)f2bf(w1.y);
      bfr[6] = (short)f2bf(w1.z); bfr[7] = (short)f2bf(w1.w);
      acc[nt] = __builtin_amdgcn_mfma_f32_16x16x32_bf16(afr, bfr, acc[nt], 0, 0, 0);
    }
  }
  ssx += __shfl_xor(ssx, 16, 64);
  ssx += __shfl_xor(ssx, 32, 64);
  if (g == 0) ssxp[w][q] = ssx;
  float s0 = 0.f, s1 = 0.f, s2a = 0.f, s3 = 0.f;
#pragma unroll
  for (int nt = 0; nt < 16; ++nt) {
    f32x4 a = acc[nt];
    s0 += a[0] * a[0]; s1 += a[1] * a[1]; s2a += a[2] * a[2]; s3 += a[3] * a[3];
  }
#pragma unroll
  for (int m = 1; m < 16; m <<= 1) {
    s0 += __shfl_xor(s0, m, 64); s1 += __shfl_xor(s1, m, 64);
    s2a += __shfl_xor(s2a, m, 64); s3 += __shfl_xor(s3, m, 64);
  }
  if (q == 0) {
    sspm[w][g * 4 + 0] = s0; sspm[w][g * 4 + 1] = s1;
    sspm[w][g * 4 + 2] = s2a; sspm[w][g * 4 + 3] = s3;
  }
  __syncthreads();
  if (tid < 16) {
    float sx = 0.f, s2 = 0.f;
#pragma unroll
    for (int ww = 0; ww < 16; ++ww) { sx += ssxp[ww][tid]; s2 += sspm[ww][tid]; }
    const float xnorm = sqrtf(sx);
    const float un = fmaxf(xnorm, 1e-5f);
    const float a0 = 0.1f * un;
    const float th = tanhf(fminf(a0, 15.f));
    const float c = th / a0;
    const float hn = th * (xnorm / a0);
    const float xn = fmaxf(hn, 1e-5f);
    const float sp = sqrtf(s2);
    float gt = 0.f;
    if (sp > 0.f) {
      const float s = c * sp;
      const float xc = fminf(0.1f * xn, 1.f - 1e-5f);
      const float at = 0.5f * logf((1.f + xc) / (1.f - xc));
      const float t = (s / xn) * at;
      const float tn = tanhf(fminf(t, 15.f));
      const float alpha = tn / (0.1f * s);
      const float rn = tn * 10.f;
      const float nrm = fmaxf(rn, 1e-5f);
      const float proj = (nrm > 9.99f) ? (9.99f / nrm) : 1.f;
      const float yn = fmaxf(rn * proj, 1e-5f);
      const float yc = fminf(0.1f * yn, 1.f - 1e-5f);
      const float at2 = 0.5f * logf((1.f + yc) / (1.f - yc));
      gt = c * alpha * proj * (at2 / (0.1f * yn));
    }
    gam[tid] = gt;
  }
  __syncthreads();
  float gr[4];
#pragma unroll
  for (int j = 0; j < 4; ++j) gr[j] = gam[g * 4 + j];
  float* orow = out + rowbase * 4096 + w * 256;
#pragma unroll
  for (int nt = 0; nt < 16; ++nt) {
    const int col = nt * 16 + q;
    f32x4 a = acc[nt];
#pragma unroll
    for (int j = 0; j < 4; ++j) orow[(size_t)(g * 4 + j) * 4096 + col] = gr[j] * a[j];
  }
}

extern "C" void kernel_launch(void* const* d_in, const int* in_sizes, int n_in,
                              void* d_out, int out_size, void* d_ws, size_t ws_size,
                              hipStream_t stream) {
  const float* x = (const float*)d_in[0];   // [4,2048,4096] f32
  const float* w = (const float*)d_in[1];   // [16,256,256] f32
  float* out = (float*)d_out;               // [4,2048,4096] f32

  const size_t wb_bytes = (size_t)16 * 8 * 16 * 64 * 8 * sizeof(ushort);  // 2 MiB
  if (ws_size >= wb_bytes) {
    ushort* wb2 = (ushort*)d_ws;
    wrepack_kernel<<<512, 256, 0, stream>>>(w, wb2);
    hyp_kernel<<<512, 1024, 0, stream>>>(x, wb2, out);
  } else {
    hyp_fallback<<<512, 1024, 0, stream>>>(x, w, out);
  }
}